// Round 1
// baseline (94.517 us; speedup 1.0000x reference)
//
#include <hip/hip_runtime.h>
#include <stdint.h>

// LstmEncoder: B=64, T=512, V=32000, E=256, U=256
// Reference semantics: mask = (x == 0); mask True = UPDATE step, otherwise
// state (h,c) carries through and out[b,t] = carried h. With x ~ U[0,32000),
// active steps are extremely rare -> state is piecewise constant per batch
// row. We exploit this exactly (same math function, data-dependent work):
//   per b: find active t's in order; run the 2-layer LSTM gate update only
//   there; output rows are piecewise-constant copies of the layer-1 h state.
//
// Grid: 64 batches x G row-splits. Each block handles rows [lo,hi) of its
// batch and redundantly replays that batch's (tiny) active-step updates.

constexpr int B_ = 64;
constexpr int T_ = 512;
constexpr int E_ = 256;
constexpr int U_ = 256;
constexpr int Z_ = 1024;           // 4*U
constexpr int G_ = 16;             // row-range splits per batch
constexpr int ROWS_ = T_ / G_;     // 32 rows per block

__device__ __forceinline__ float sigmoid_f(float v) {
    return 1.0f / (1.0f + expf(-v));
}

__global__ __launch_bounds__(256) void lstm_enc(
    const int*   __restrict__ x,
    const float* __restrict__ emb,
    const float* __restrict__ k0, const float* __restrict__ r0, const float* __restrict__ b0,
    const float* __restrict__ k1, const float* __restrict__ r1, const float* __restrict__ b1,
    float* __restrict__ out)
{
    __shared__ int x_sh[T_];
    __shared__ unsigned long long mask_sh[T_ / 64];
    __shared__ short list_sh[T_];
    __shared__ int n_sh;
    __shared__ __align__(16) float h0s[U_];
    __shared__ __align__(16) float h1s[U_];
    __shared__ __align__(16) float v0s[U_];

    const int tid = threadIdx.x;          // 0..255, owns unit `tid`
    const int b   = blockIdx.x >> 4;      // batch
    const int g   = blockIdx.x & (G_ - 1);
    const int lo  = g * ROWS_;
    const int hi  = lo + ROWS_;

    // ---- load token row, init states ----
    for (int t = tid; t < T_; t += 256) x_sh[t] = x[b * T_ + t];
    h0s[tid] = 0.0f;
    h1s[tid] = 0.0f;
    float c0 = 0.0f, c1 = 0.0f;           // cell state: private to unit owner
    __syncthreads();

    // ---- build ordered active-step list (x==0 -> update) via wave64 ballot ----
#pragma unroll
    for (int pass = 0; pass < T_ / 256; ++pass) {
        const int t = pass * 256 + tid;
        const unsigned long long bm = __ballot(x_sh[t] == 0);
        if ((tid & 63) == 0) mask_sh[pass * 4 + (tid >> 6)] = bm;
    }
    __syncthreads();
    if (tid == 0) {
        int n = 0;
        for (int w = 0; w < T_ / 64; ++w) {
            unsigned long long bits = mask_sh[w];
            while (bits) {
                const int p = __builtin_ctzll(bits);
                list_sh[n++] = (short)(w * 64 + p);
                bits &= bits - 1;
            }
        }
        n_sh = n;
    }
    __syncthreads();
    const int n_act = n_sh;

    int wp = lo;  // next output row this block still has to write

    for (int i = 0; i < n_act; ++i) {
        const int t = (int)list_sh[i];
        if (t >= hi) break;               // uniform per block

        // rows [wp, t) get the current (pre-update) h1 state
        for (int tr = wp + (tid >> 6); tr < t; tr += 4) {
            const int q = (tid & 63) * 4;
            const float4 v = *reinterpret_cast<const float4*>(&h1s[q]);
            *reinterpret_cast<float4*>(&out[((size_t)(b * T_ + tr)) * U_ + q]) = v;
        }
        if (t > wp) wp = t;

        __syncthreads();                  // row writes done reading h1s
        const int tok = x_sh[t];
        v0s[tid] = emb[(size_t)tok * E_ + tid];
        __syncthreads();

        // ---- layer 0: z = v0 @ k0 + b0 + h0 @ r0 ; gates i,f,g,o ----
        float zi = b0[tid], zf = b0[tid + 256], zg = b0[tid + 512], zo = b0[tid + 768];
        for (int k = 0; k < U_; ++k) {
            const float a = v0s[k];
            const float h = h0s[k];
            const float* Kp = k0 + (size_t)k * Z_ + tid;
            const float* Rp = r0 + (size_t)k * Z_ + tid;
            zi += a * Kp[0]   + h * Rp[0];
            zf += a * Kp[256] + h * Rp[256];
            zg += a * Kp[512] + h * Rp[512];
            zo += a * Kp[768] + h * Rp[768];
        }
        {
            const float ig = sigmoid_f(zi), fg = sigmoid_f(zf);
            const float gg = tanhf(zg),     og = sigmoid_f(zo);
            const float cn = fg * c0 + ig * gg;
            const float hn = og * tanhf(cn);
            __syncthreads();              // everyone done reading h0s
            c0 = cn;
            h0s[tid] = hn;
            __syncthreads();
        }

        // ---- layer 1: input = updated h0 ----
        float yi = b1[tid], yf = b1[tid + 256], yg = b1[tid + 512], yo = b1[tid + 768];
        for (int k = 0; k < U_; ++k) {
            const float a = h0s[k];
            const float h = h1s[k];
            const float* Kp = k1 + (size_t)k * Z_ + tid;
            const float* Rp = r1 + (size_t)k * Z_ + tid;
            yi += a * Kp[0]   + h * Rp[0];
            yf += a * Kp[256] + h * Rp[256];
            yg += a * Kp[512] + h * Rp[512];
            yo += a * Kp[768] + h * Rp[768];
        }
        {
            const float ig = sigmoid_f(yi), fg = sigmoid_f(yf);
            const float gg = tanhf(yg),     og = sigmoid_f(yo);
            const float cn = fg * c1 + ig * gg;
            const float hn = og * tanhf(cn);
            __syncthreads();              // everyone done reading h1s
            c1 = cn;
            h1s[tid] = hn;
            __syncthreads();
        }
    }

    // tail rows [wp, hi) get the final-for-this-range h1 state
    for (int tr = wp + (tid >> 6); tr < hi; tr += 4) {
        const int q = (tid & 63) * 4;
        const float4 v = *reinterpret_cast<const float4*>(&h1s[q]);
        *reinterpret_cast<float4*>(&out[((size_t)(b * T_ + tr)) * U_ + q]) = v;
    }

    // final hT (layer 1) -> out[B*T*U + b*U .. +U)
    if (g == G_ - 1 && tid < 64) {
        const float4 v = *reinterpret_cast<const float4*>(&h1s[tid * 4]);
        *reinterpret_cast<float4*>(&out[(size_t)B_ * T_ * U_ + (size_t)b * U_ + tid * 4]) = v;
    }
}

extern "C" void kernel_launch(void* const* d_in, const int* in_sizes, int n_in,
                              void* d_out, int out_size, void* d_ws, size_t ws_size,
                              hipStream_t stream) {
    const int*   x   = (const int*)  d_in[0];
    const float* emb = (const float*)d_in[1];
    const float* k0  = (const float*)d_in[2];
    const float* r0  = (const float*)d_in[3];
    const float* b0  = (const float*)d_in[4];
    const float* k1  = (const float*)d_in[5];
    const float* r1  = (const float*)d_in[6];
    const float* b1  = (const float*)d_in[7];
    float* out = (float*)d_out;

    dim3 grid(B_ * G_);   // 1024 blocks
    dim3 block(256);
    lstm_enc<<<grid, block, 0, stream>>>(x, emb, k0, r0, b0, k1, r1, b1, out);
}